// Round 13
// baseline (98.323 us; speedup 1.0000x reference)
//
#include <hip/hip_runtime.h>

#define BB 512
#define NN 64
#define EE 64
#define DD 256
#define BND (BB * NN * DD)
#define SA 68

typedef __attribute__((ext_vector_type(8))) short s8v;
typedef __attribute__((ext_vector_type(4))) float f4v;
typedef __attribute__((ext_vector_type(8))) unsigned short u16x8;

__device__ __forceinline__ unsigned short f2bf(float f) {
    unsigned int x = __float_as_uint(f);
    x = x + 0x7fffu + ((x >> 16) & 1u);   // RNE
    return (unsigned short)(x >> 16);
}
__device__ __forceinline__ float bf2f(unsigned short u) {
    return __uint_as_float(((unsigned int)u) << 16);
}
__device__ __forceinline__ float lrelu(float v) { return v > 0.f ? v : 0.2f * v; }

// ws byte offsets
#define WS_PREP   0          // 2048 f32 (8KB)
#define WS_P3B    8192       // 256 f32
#define WS_WFRAG  12288      // 65536 bf16 (128KB)
#define WS_DV     143360     // 512*384 f32 (768KB)
#define WS_MASKS  929792     // 512*128 u64 (512KB)
#define WS_M      1454080    // 512*4096 bf16 (8MB)
#define WS_X0     5648384    // 512*64*256 bf16 (32MB... 16MB)

// prep layout (floats): [0)p1a [256)p2a [512)p3a [768]c0a [1024)p1b [1280)p2b [1536)wp3b [1792]c0b
__global__ void prep_dots(const float* __restrict__ w2a, const float* __restrict__ w3a,
                          const float* __restrict__ aa, const float* __restrict__ a2a,
                          const float* __restrict__ wca,
                          const float* __restrict__ w2b, const float* __restrict__ w3b,
                          const float* __restrict__ ab, const float* __restrict__ a2b,
                          const float* __restrict__ wcb,
                          float* __restrict__ prep, float* __restrict__ p3b_ws) {
    const int t = threadIdx.x;
    const int blk = blockIdx.x;
    const int layer = blk >> 3;
    const int r0 = (blk & 7) * 32;
    __shared__ float vhi[256], v2lo[256], v2hi[256], red[256];
    const float* w2 = layer ? w2b : w2a;
    const float* w3 = layer ? w3b : w3a;
    const float* av = layer ? ab : aa;
    const float* a2 = layer ? a2b : a2a;
    vhi[t] = av[256 + t];
    v2lo[t] = a2[t];
    v2hi[t] = a2[256 + t];
    __syncthreads();
    const int row = r0 + (t >> 3), q = t & 7;
    const float* w2r = w2 + (size_t)row * DD + q * 32;
    const float* w3r = w3 + (size_t)row * DD + q * 32;
    float s1 = 0.f, s2 = 0.f, s3 = 0.f;
    #pragma unroll
    for (int c = 0; c < 8; c++) {
        float4 v = *(const float4*)&w2r[c * 4];
        float4 u = *(const float4*)&w3r[c * 4];
        float4 p1 = *(const float4*)&vhi[q * 32 + c * 4];
        float4 p2 = *(const float4*)&v2lo[q * 32 + c * 4];
        float4 p3 = *(const float4*)&v2hi[q * 32 + c * 4];
        s1 = fmaf(v.x, p1.x, fmaf(v.y, p1.y, fmaf(v.z, p1.z, fmaf(v.w, p1.w, s1))));
        s2 = fmaf(v.x, p2.x, fmaf(v.y, p2.y, fmaf(v.z, p2.z, fmaf(v.w, p2.w, s2))));
        s3 = fmaf(u.x, p3.x, fmaf(u.y, p3.y, fmaf(u.z, p3.z, fmaf(u.w, p3.w, s3))));
    }
    s1 += __shfl_xor(s1, 1); s1 += __shfl_xor(s1, 2); s1 += __shfl_xor(s1, 4);
    s2 += __shfl_xor(s2, 1); s2 += __shfl_xor(s2, 2); s2 += __shfl_xor(s2, 4);
    s3 += __shfl_xor(s3, 1); s3 += __shfl_xor(s3, 2); s3 += __shfl_xor(s3, 4);
    if (q == 0) {
        if (layer == 0) { prep[row] = s1; prep[256 + row] = s2; prep[512 + row] = s3; }
        else { prep[1024 + row] = s1; prep[1280 + row] = s2; p3b_ws[row] = s3; }
    }
    if ((blk & 7) == 0) {
        red[t] = layer ? (wcb[t] * ab[t]) : (wca[t] * aa[t]);
        __syncthreads();
        for (int o = 128; o > 0; o >>= 1) { if (t < o) red[t] += red[t + o]; __syncthreads(); }
        if (t == 0) prep[layer ? 1792 : 768] = red[0];
    }
}

// blocks 0..7: wp3b = wtr @ p3b ; blocks 8..39: pack g2_w into MFMA B-fragments
__global__ void prep2_pack(const float* __restrict__ wtr, const float* __restrict__ p3b_ws,
                           float* __restrict__ prep, unsigned short* __restrict__ wfrag) {
    const int t = threadIdx.x, blk = blockIdx.x;
    __shared__ float p3[256];
    if (blk < 8) {
        p3[t] = p3b_ws[t];
        __syncthreads();
        const int row = blk * 32 + (t >> 3), q = t & 7;
        const float* wr = wtr + (size_t)row * DD + q * 32;
        float s = 0.f;
        #pragma unroll
        for (int c = 0; c < 8; c++) {
            float4 v = *(const float4*)&wr[c * 4];
            float4 p = *(const float4*)&p3[q * 32 + c * 4];
            s = fmaf(v.x, p.x, fmaf(v.y, p.y, fmaf(v.z, p.z, fmaf(v.w, p.w, s))));
        }
        s += __shfl_xor(s, 1); s += __shfl_xor(s, 2); s += __shfl_xor(s, 4);
        if (q == 0) prep[1536 + row] = s;
    } else {
        int gid = (blk - 8) * 256 + t;      // 0..8191
        int l = gid & 63, frag = gid >> 6;
        int kc = frag >> 4, nt = frag & 15;
        int kb = kc * 32 + (l >> 4) * 8;
        int n = nt * 16 + (l & 15);
        u16x8 u;
        #pragma unroll
        for (int j = 0; j < 8; j++) u[j] = f2bf(wtr[(size_t)(kb + j) * DD + n]);
        *(u16x8*)(wfrag + (size_t)gid * 8) = u;
    }
}

// K1: streaming — per batch: emb gather -> dv (f32 dots) + x0bf ws; nodes2 copy; masks
__launch_bounds__(256, 4)
__global__ void k1_stage(const int* __restrict__ inputs, const int* __restrict__ HT,
                         const float* __restrict__ emb_w, const float* __restrict__ emb2_w,
                         const float* __restrict__ prep,
                         float* __restrict__ dv_ws, unsigned long long* __restrict__ masks,
                         unsigned short* __restrict__ x0bf, float* __restrict__ out) {
    __shared__ float pvs[1536];
    __shared__ unsigned long long mEs[64];
    const int b = blockIdx.x;
    const int t = threadIdx.x;
    const int lane = t & 63;
    const int w4 = t >> 6;
    const int row = t >> 2, q4 = t & 3;
    for (int i = t; i < 1536; i += 256) {
        int off = i + (((i >> 8) >= 3) ? 256 : 0);
        pvs[i] = prep[off];
    }
    const int idx = inputs[b * 64 + row];
    __syncthreads();
    // x0 row chunk (64 cols) + 6 dots + bf16 store
    {
        const float4* src = (const float4*)(emb_w + (size_t)idx * DD + q4 * 64);
        float a6[6] = {0.f, 0.f, 0.f, 0.f, 0.f, 0.f};
        unsigned short* xd = x0bf + ((size_t)(b * 64 + row)) * DD + q4 * 64;
        #pragma unroll
        for (int c = 0; c < 16; c++) {
            float4 v = src[c];
            ushort4 u;
            u.x = f2bf(v.x); u.y = f2bf(v.y); u.z = f2bf(v.z); u.w = f2bf(v.w);
            *(ushort4*)(xd + c * 4) = u;
            #pragma unroll
            for (int j = 0; j < 6; j++) {
                float4 p = *(const float4*)&pvs[j * 256 + q4 * 64 + c * 4];
                a6[j] = fmaf(v.x, p.x, fmaf(v.y, p.y, fmaf(v.z, p.z, fmaf(v.w, p.w, a6[j]))));
            }
        }
        #pragma unroll
        for (int j = 0; j < 6; j++) {
            a6[j] += __shfl_xor(a6[j], 1);
            a6[j] += __shfl_xor(a6[j], 2);
        }
        if (q4 == 0) {
            #pragma unroll
            for (int j = 0; j < 6; j++) dv_ws[b * 384 + j * 64 + row] = a6[j];
        }
    }
    // nodes2 copy
    {
        const float4* s2 = (const float4*)(emb2_w + (size_t)idx * DD + q4 * 64);
        float4* d2 = (float4*)(out + (size_t)2 * BND + (size_t)(b * 64 + row) * DD + q4 * 64);
        #pragma unroll
        for (int c = 0; c < 16; c++) d2[c] = s2[c];
    }
    // edge masks
    #pragma unroll
    for (int i = 0; i < 16; i++) {
        int e = w4 * 16 + i;
        int h = HT[((size_t)b * EE + e) * NN + lane];
        unsigned long long m = __ballot(h > 0);
        if (lane == 0) mEs[e] = m;
    }
    __syncthreads();
    if (t < 64) {
        unsigned long long acc = 0ull;
        for (int e = 0; e < 64; e++) acc |= ((mEs[e] >> t) & 1ull) << e;
        masks[b * 128 + t] = mEs[t];
        masks[b * 128 + 64 + t] = acc;
    }
}

// K2: the softmax -> M chain (P2..P9). 31KB LDS, VGPR<=64 -> high residency.
__launch_bounds__(512, 8)
__global__ void k2_chain(const float* __restrict__ dv_ws,
                         const unsigned long long* __restrict__ masks,
                         const float* __restrict__ prep, unsigned short* __restrict__ Mws) {
    __shared__ unsigned short RA[64 * SA];   // Pe^T
    __shared__ unsigned short RBC[64 * SA];  // Pe row -> Pn' row -> C2 row (merged lifetimes)
    __shared__ unsigned short RD[64 * SA];   // C1'^T
    __shared__ unsigned short XT[16 * SA];   // ext B-tile
    __shared__ float dvs[384];
    __shared__ float db2[192];
    __shared__ float u1f[64], invdef[64];
    __shared__ unsigned long long mE[64], mN[64];

    const int b = blockIdx.x;
    const int t = threadIdx.x;
    const int lane = t & 63;
    const int w8 = t >> 6;
    const int l15 = lane & 15, lh = lane >> 4;

    if (t < 384) dvs[t] = dv_ws[b * 384 + t];
    else if (t < 448) mE[t - 384] = masks[b * 128 + (t - 384)];
    else mN[t - 448] = masks[b * 128 + 64 + (t - 448)];
    for (int i = t; i < 16 * SA; i += 512) XT[i] = 0;
    __syncthreads();

    const int wr = (w8 & 3) * 16;
    const int wc = (w8 >> 2) * 32;
    const int row0 = wr + lh * 4;

    // ---- P2: Pe1 -> RA (^T) + RBC (row) ----
    {
        float s1l = lrelu(prep[768] + dvs[lane]);
        float g1 = s1l;
        #pragma unroll
        for (int o = 32; o > 0; o >>= 1) g1 = fmaxf(g1, __shfl_xor(g1, o));
        float E1 = __expf(s1l - g1);
        #pragma unroll
        for (int i = 0; i < 8; i++) {
            int e = w8 * 8 + i;
            unsigned long long me = mE[e];
            float pe = (me == 0ull) ? 1.f : (((me >> lane) & 1ull) ? E1 : 0.f);
            unsigned short bf = f2bf(pe);
            RA[lane * SA + e] = bf;
            RBC[e * SA + lane] = bf;
        }
    }
    __syncthreads();

    // ---- P2b: [De;We;g3;g4;g5] (waves 0-3) ----
    if (w8 < 4) {
        const int etile = w8 * 16;
        f4v acc = {0.f, 0.f, 0.f, 0.f};
        #pragma unroll
        for (int kc = 0; kc < 2; kc++) {
            u16x8 au;
            #pragma unroll
            for (int jj = 0; jj < 8; jj++) {
                int k = kc * 32 + lh * 8 + jj;
                float v = (l15 == 0) ? 1.f : ((l15 <= 4) ? dvs[(l15 + 1) * 64 + k] : 0.f);
                au[jj] = f2bf(v);
            }
            s8v bv = *(const s8v*)&RBC[(etile + l15) * SA + kc * 32 + lh * 8];
            acc = __builtin_amdgcn_mfma_f32_16x16x32_bf16((s8v)au, bv, acc, 0, 0, 0);
        }
        int e = etile + l15;
        if (lh == 0) {
            float De = acc[0], We = acc[1];
            invdef[e] = 1.f / De;
            u1f[e] = We / De;
            XT[e] = f2bf(De);
            XT[1 * SA + e] = f2bf(acc[2]);
            XT[2 * SA + e] = f2bf(acc[3]);
        } else if (lh == 1) {
            XT[3 * SA + e] = f2bf(acc[0]);
        }
    }
    __syncthreads();

    // ---- P3: Pn1' -> RBC (overwrite Pe1 rows) ----
    {
        float t2l = dvs[64 + lane];
        float gt2 = t2l;
        #pragma unroll
        for (int o = 32; o > 0; o >>= 1) gt2 = fmaxf(gt2, __shfl_xor(gt2, o));
        float um = u1f[lane];
        #pragma unroll
        for (int o = 32; o > 0; o >>= 1) um = fmaxf(um, __shfl_xor(um, o));
        float M1 = lrelu(gt2 + um);
        float ul = u1f[lane];
        float ide = invdef[lane];
        #pragma unroll
        for (int i = 0; i < 8; i++) {
            int n = w8 * 8 + i;
            unsigned long long mn = mN[n];
            float t2n = dvs[64 + n];
            float pr = (mn == 0ull) ? 1.f
                     : (((mn >> lane) & 1ull) ? __expf(lrelu(t2n + ul) - M1) : 0.f);
            RBC[n * SA + lane] = f2bf(pr * ide);
        }
    }
    __syncthreads();

    // ---- P4: C1' + Dn + db2 -> RD ----
    {
        f4v a0 = {0.f,0.f,0.f,0.f}, a1 = {0.f,0.f,0.f,0.f}, ax = {0.f,0.f,0.f,0.f};
        #pragma unroll
        for (int kc = 0; kc < 2; kc++) {
            s8v a  = *(const s8v*)&RBC[(wr + l15) * SA + kc * 32 + lh * 8];
            s8v b0 = *(const s8v*)&RA[(wc + l15) * SA + kc * 32 + lh * 8];
            s8v b1 = *(const s8v*)&RA[(wc + 16 + l15) * SA + kc * 32 + lh * 8];
            s8v bx = *(const s8v*)&XT[l15 * SA + kc * 32 + lh * 8];
            a0 = __builtin_amdgcn_mfma_f32_16x16x32_bf16(a, b0, a0, 0, 0, 0);
            a1 = __builtin_amdgcn_mfma_f32_16x16x32_bf16(a, b1, a1, 0, 0, 0);
            ax = __builtin_amdgcn_mfma_f32_16x16x32_bf16(a, bx, ax, 0, 0, 0);
        }
        float invdn[4];
        #pragma unroll
        for (int rg = 0; rg < 4; rg++) invdn[rg] = 1.f / __shfl(ax[rg], lh << 4);
        int col0 = wc + l15, col1 = wc + 16 + l15;
        ushort4 u0, u1;
        #pragma unroll
        for (int rg = 0; rg < 4; rg++) {
            ((unsigned short*)&u0)[rg] = f2bf(a0[rg] * invdn[rg] + ((row0 + rg) == col0 ? 1.f : 0.f));
            ((unsigned short*)&u1)[rg] = f2bf(a1[rg] * invdn[rg] + ((row0 + rg) == col1 ? 1.f : 0.f));
        }
        *(ushort4*)&RD[col0 * SA + row0] = u0;
        *(ushort4*)&RD[col1 * SA + row0] = u1;
        if (w8 < 4 && l15 >= 1 && l15 <= 3) {
            int jj = l15 - 1;
            #pragma unroll
            for (int rg = 0; rg < 4; rg++)
                db2[jj * 64 + row0 + rg] = ax[rg] * invdn[rg] + dvs[(jj + 3) * 64 + row0 + rg];
        }
    }
    __syncthreads();

    // ---- P6: Pe2 -> RA (^T) + RBC (row) ----
    {
        float s2l = lrelu(prep[1792] + db2[lane]);
        float g2 = s2l;
        #pragma unroll
        for (int o = 32; o > 0; o >>= 1) g2 = fmaxf(g2, __shfl_xor(g2, o));
        float E2 = __expf(s2l - g2);
        #pragma unroll
        for (int i = 0; i < 8; i++) {
            int e = w8 * 8 + i;
            unsigned long long me = mE[e];
            float pe = (me == 0ull) ? 1.f : (((me >> lane) & 1ull) ? E2 : 0.f);
            unsigned short bf = f2bf(pe);
            RA[lane * SA + e] = bf;
            RBC[e * SA + lane] = bf;
        }
    }
    __syncthreads();

    // ---- P6b: [De2;We2] (waves 0-3) ----
    if (w8 < 4) {
        const int etile = w8 * 16;
        f4v acc = {0.f, 0.f, 0.f, 0.f};
        #pragma unroll
        for (int kc = 0; kc < 2; kc++) {
            u16x8 au;
            #pragma unroll
            for (int jj = 0; jj < 8; jj++) {
                int k = kc * 32 + lh * 8 + jj;
                float v = (l15 == 0) ? 1.f : ((l15 == 1) ? db2[128 + k] : 0.f);
                au[jj] = f2bf(v);
            }
            s8v bv = *(const s8v*)&RBC[(etile + l15) * SA + kc * 32 + lh * 8];
            acc = __builtin_amdgcn_mfma_f32_16x16x32_bf16((s8v)au, bv, acc, 0, 0, 0);
        }
        if (lh == 0) {
            int e = etile + l15;
            float De = acc[0], We = acc[1];
            invdef[e] = 1.f / De;
            u1f[e] = We / De;
            XT[e] = f2bf(De);
        }
    }
    __syncthreads();

    // ---- P7: Pn2' -> RBC ----
    {
        float d1l = db2[64 + lane];
        float gd1 = d1l;
        #pragma unroll
        for (int o = 32; o > 0; o >>= 1) gd1 = fmaxf(gd1, __shfl_xor(gd1, o));
        float um = u1f[lane];
        #pragma unroll
        for (int o = 32; o > 0; o >>= 1) um = fmaxf(um, __shfl_xor(um, o));
        float M2 = lrelu(gd1 + um);
        float ul = u1f[lane];
        float ide = invdef[lane];
        #pragma unroll
        for (int i = 0; i < 8; i++) {
            int n = w8 * 8 + i;
            unsigned long long mn = mN[n];
            float d1n = db2[64 + n];
            float pr = (mn == 0ull) ? 1.f
                     : (((mn >> lane) & 1ull) ? __expf(lrelu(d1n + ul) - M2) : 0.f);
            RBC[n * SA + lane] = f2bf(pr * ide);
        }
    }
    __syncthreads();

    // ---- P8: C2 = Dn2^-1 (Pn2' @ Pe2) -> regs -> RBC ----
    {
        f4v a0 = {0.f,0.f,0.f,0.f}, a1 = {0.f,0.f,0.f,0.f}, ax = {0.f,0.f,0.f,0.f};
        #pragma unroll
        for (int kc = 0; kc < 2; kc++) {
            s8v a  = *(const s8v*)&RBC[(wr + l15) * SA + kc * 32 + lh * 8];
            s8v b0 = *(const s8v*)&RA[(wc + l15) * SA + kc * 32 + lh * 8];
            s8v b1 = *(const s8v*)&RA[(wc + 16 + l15) * SA + kc * 32 + lh * 8];
            s8v bx = *(const s8v*)&XT[l15 * SA + kc * 32 + lh * 8];
            a0 = __builtin_amdgcn_mfma_f32_16x16x32_bf16(a, b0, a0, 0, 0, 0);
            a1 = __builtin_amdgcn_mfma_f32_16x16x32_bf16(a, b1, a1, 0, 0, 0);
            ax = __builtin_amdgcn_mfma_f32_16x16x32_bf16(a, bx, ax, 0, 0, 0);
        }
        float invdn[4];
        #pragma unroll
        for (int rg = 0; rg < 4; rg++) invdn[rg] = 1.f / __shfl(ax[rg], lh << 4);
        __syncthreads();   // all P8 A-reads of RBC done before overwrite
        #pragma unroll
        for (int rg = 0; rg < 4; rg++) {
            RBC[(row0 + rg) * SA + wc + l15] = f2bf(a0[rg] * invdn[rg]);
            RBC[(row0 + rg) * SA + wc + 16 + l15] = f2bf(a1[rg] * invdn[rg]);
        }
    }
    __syncthreads();

    // ---- P9: M = C2 @ C1' -> Mws (global) ----
    {
        f4v a0 = {0.f,0.f,0.f,0.f}, a1 = {0.f,0.f,0.f,0.f};
        #pragma unroll
        for (int kc = 0; kc < 2; kc++) {
            s8v a  = *(const s8v*)&RBC[(wr + l15) * SA + kc * 32 + lh * 8];
            s8v b0 = *(const s8v*)&RD[(wc + l15) * SA + kc * 32 + lh * 8];
            s8v b1 = *(const s8v*)&RD[(wc + 16 + l15) * SA + kc * 32 + lh * 8];
            a0 = __builtin_amdgcn_mfma_f32_16x16x32_bf16(a, b0, a0, 0, 0, 0);
            a1 = __builtin_amdgcn_mfma_f32_16x16x32_bf16(a, b1, a1, 0, 0, 0);
        }
        unsigned short* md = Mws + (size_t)b * 4096;
        #pragma unroll
        for (int rg = 0; rg < 4; rg++) {
            md[(row0 + rg) * 64 + wc + l15] = f2bf(a0[rg]);
            md[(row0 + rg) * 64 + wc + 16 + l15] = f2bf(a1[rg]);
        }
    }
}

// K3: GEMM1 (x0@w) + GEMM2 (M@Y) + residual + dual out-write
__launch_bounds__(512, 4)
__global__ void k3_out(const unsigned short* __restrict__ x0bf,
                       const unsigned short* __restrict__ Mws,
                       const unsigned short* __restrict__ wfrag,
                       float* __restrict__ out) {
    __shared__ unsigned short bufA[256 * SA];   // x0 [64][264] -> YT [256][68]
    __shared__ unsigned short Mlds[64 * SA];
    const int b = blockIdx.x;
    const int t = threadIdx.x;
    const int lane = t & 63;
    const int w8 = t >> 6;
    const int l15 = lane & 15, lh = lane >> 4;

    {
        const u16x8* xsrc = (const u16x8*)(x0bf + (size_t)b * 64 * DD);
        #pragma unroll
        for (int c = 0; c < 4; c++) {
            int i = t + 512 * c;
            int n = i >> 5, cc = i & 31;
            *(u16x8*)&bufA[n * 264 + cc * 8] = xsrc[i];
        }
        u16x8 mv = ((const u16x8*)(Mws + (size_t)b * 4096))[t];
        *(u16x8*)&Mlds[(t >> 3) * SA + (t & 7) * 8] = mv;
    }
    __syncthreads();

    const int wr = (w8 & 3) * 16;
    const int row0 = wr + lh * 4;
    const int cb8 = (w8 >> 2) * 8;

    unsigned short rres[8][4];
    {
        f4v acc[8];
        #pragma unroll
        for (int nt = 0; nt < 8; nt++) acc[nt] = (f4v){0.f, 0.f, 0.f, 0.f};
        const s8v* wf = (const s8v*)wfrag;
        #pragma unroll
        for (int kc = 0; kc < 8; kc++) {
            s8v a = *(const s8v*)&bufA[(wr + l15) * 264 + kc * 32 + lh * 8];
            #pragma unroll
            for (int nt = 0; nt < 8; nt++) {
                s8v bv = wf[(size_t)(kc * 16 + cb8 + nt) * 64 + lane];
                acc[nt] = __builtin_amdgcn_mfma_f32_16x16x32_bf16(a, bv, acc[nt], 0, 0, 0);
            }
        }
        #pragma unroll
        for (int nt = 0; nt < 8; nt++) {
            #pragma unroll
            for (int rg = 0; rg < 4; rg++)
                rres[nt][rg] = bufA[(row0 + rg) * 264 + (cb8 + nt) * 16 + l15];
        }
        __syncthreads();   // x0 dead -> YT overlay
        #pragma unroll
        for (int nt = 0; nt < 8; nt++) {
            int feat = (cb8 + nt) * 16 + l15;
            ushort4 u;
            u.x = f2bf(acc[nt][0]); u.y = f2bf(acc[nt][1]);
            u.z = f2bf(acc[nt][2]); u.w = f2bf(acc[nt][3]);
            *(ushort4*)&bufA[feat * SA + row0] = u;
        }
    }
    __syncthreads();

    {
        f4v acc2[8];
        #pragma unroll
        for (int nt = 0; nt < 8; nt++) acc2[nt] = (f4v){0.f, 0.f, 0.f, 0.f};
        #pragma unroll
        for (int kc = 0; kc < 2; kc++) {
            s8v a = *(const s8v*)&Mlds[(wr + l15) * SA + kc * 32 + lh * 8];
            #pragma unroll
            for (int nt = 0; nt < 8; nt++) {
                s8v bv = *(const s8v*)&bufA[((cb8 + nt) * 16 + l15) * SA + kc * 32 + lh * 8];
                acc2[nt] = __builtin_amdgcn_mfma_f32_16x16x32_bf16(a, bv, acc2[nt], 0, 0, 0);
            }
        }
        #pragma unroll
        for (int nt = 0; nt < 8; nt++) {
            #pragma unroll
            for (int rg = 0; rg < 4; rg++) {
                int row = row0 + rg;
                int colg = (cb8 + nt) * 16 + l15;
                float v = acc2[nt][rg] + bf2f(rres[nt][rg]);
                size_t o = (size_t)(b * 64 + row) * DD + colg;
                out[o] = v;
                out[BND + o] = v;
            }
        }
    }
}

extern "C" void kernel_launch(void* const* d_in, const int* in_sizes, int n_in,
                              void* d_out, int out_size, void* d_ws, size_t ws_size,
                              hipStream_t stream) {
    const int* inputs = (const int*)d_in[0];
    const int* HT = (const int*)d_in[1];
    const float* emb_w  = (const float*)d_in[4];
    const float* emb2_w = (const float*)d_in[5];
    const float* g1_w2 = (const float*)d_in[6];
    const float* g1_w3 = (const float*)d_in[7];
    const float* g1_a  = (const float*)d_in[8];
    const float* g1_a2 = (const float*)d_in[9];
    const float* g1_wc = (const float*)d_in[10];
    const float* g2_w  = (const float*)d_in[11];
    const float* g2_w2 = (const float*)d_in[12];
    const float* g2_w3 = (const float*)d_in[13];
    const float* g2_a  = (const float*)d_in[14];
    const float* g2_a2 = (const float*)d_in[15];
    const float* g2_wc = (const float*)d_in[16];

    float* out = (float*)d_out;
    float* prep = (float*)((char*)d_ws + WS_PREP);
    float* p3b_ws = (float*)((char*)d_ws + WS_P3B);
    unsigned short* wfrag = (unsigned short*)((char*)d_ws + WS_WFRAG);
    float* dv_ws = (float*)((char*)d_ws + WS_DV);
    unsigned long long* masks = (unsigned long long*)((char*)d_ws + WS_MASKS);
    unsigned short* Mws = (unsigned short*)((char*)d_ws + WS_M);
    unsigned short* x0bf = (unsigned short*)((char*)d_ws + WS_X0);

    prep_dots<<<16, 256, 0, stream>>>(g1_w2, g1_w3, g1_a, g1_a2, g1_wc,
                                      g2_w2, g2_w3, g2_a, g2_a2, g2_wc,
                                      prep, p3b_ws);
    prep2_pack<<<40, 256, 0, stream>>>(g2_w, p3b_ws, prep, wfrag);
    k1_stage<<<BB, 256, 0, stream>>>(inputs, HT, emb_w, emb2_w, prep,
                                     dv_ws, masks, x0bf, out);
    k2_chain<<<BB, 512, 0, stream>>>(dv_ws, masks, prep, Mws);
    k3_out<<<BB, 512, 0, stream>>>(x0bf, Mws, wfrag, out);
}

// Round 14
// 63.693 us; speedup vs baseline: 1.5437x; 1.5437x over previous
//
#include <hip/hip_runtime.h>

#define BB 512
#define NN 64
#define EE 64
#define DD 256
#define BND (BB * NN * DD)
#define SA 68

typedef __attribute__((ext_vector_type(8))) short s8v;
typedef __attribute__((ext_vector_type(4))) float f4v;
typedef __attribute__((ext_vector_type(8))) unsigned short u16x8;

__device__ __forceinline__ unsigned short f2bf(float f) {
    unsigned int x = __float_as_uint(f);
    x = x + 0x7fffu + ((x >> 16) & 1u);   // RNE
    return (unsigned short)(x >> 16);
}
__device__ __forceinline__ float bf2f(unsigned short u) {
    return __uint_as_float(((unsigned int)u) << 16);
}
__device__ __forceinline__ float lrelu(float v) { return v > 0.f ? v : 0.2f * v; }

// ws byte offsets
#define WS_PREP  0          // 2048 f32 (8KB)
#define WS_P3B   8192       // 256 f32
#define WS_WFRAG 12288      // 65536 bf16 (128KB)

// prep layout (floats): [0)p1a [256)p2a [512)p3a [768]c0a [1024)p1b [1280)p2b [1536)wp3b [1792]c0b
__global__ void prep_dots(const float* __restrict__ w2a, const float* __restrict__ w3a,
                          const float* __restrict__ aa, const float* __restrict__ a2a,
                          const float* __restrict__ wca,
                          const float* __restrict__ w2b, const float* __restrict__ w3b,
                          const float* __restrict__ ab, const float* __restrict__ a2b,
                          const float* __restrict__ wcb,
                          float* __restrict__ prep, float* __restrict__ p3b_ws) {
    const int t = threadIdx.x;
    const int blk = blockIdx.x;
    const int layer = blk >> 3;
    const int r0 = (blk & 7) * 32;
    __shared__ float vhi[256], v2lo[256], v2hi[256], red[256];
    const float* w2 = layer ? w2b : w2a;
    const float* w3 = layer ? w3b : w3a;
    const float* av = layer ? ab : aa;
    const float* a2 = layer ? a2b : a2a;
    vhi[t] = av[256 + t];
    v2lo[t] = a2[t];
    v2hi[t] = a2[256 + t];
    __syncthreads();
    const int row = r0 + (t >> 3), q = t & 7;
    const float* w2r = w2 + (size_t)row * DD + q * 32;
    const float* w3r = w3 + (size_t)row * DD + q * 32;
    float s1 = 0.f, s2 = 0.f, s3 = 0.f;
    #pragma unroll
    for (int c = 0; c < 8; c++) {
        float4 v = *(const float4*)&w2r[c * 4];
        float4 u = *(const float4*)&w3r[c * 4];
        float4 p1 = *(const float4*)&vhi[q * 32 + c * 4];
        float4 p2 = *(const float4*)&v2lo[q * 32 + c * 4];
        float4 p3 = *(const float4*)&v2hi[q * 32 + c * 4];
        s1 = fmaf(v.x, p1.x, fmaf(v.y, p1.y, fmaf(v.z, p1.z, fmaf(v.w, p1.w, s1))));
        s2 = fmaf(v.x, p2.x, fmaf(v.y, p2.y, fmaf(v.z, p2.z, fmaf(v.w, p2.w, s2))));
        s3 = fmaf(u.x, p3.x, fmaf(u.y, p3.y, fmaf(u.z, p3.z, fmaf(u.w, p3.w, s3))));
    }
    s1 += __shfl_xor(s1, 1); s1 += __shfl_xor(s1, 2); s1 += __shfl_xor(s1, 4);
    s2 += __shfl_xor(s2, 1); s2 += __shfl_xor(s2, 2); s2 += __shfl_xor(s2, 4);
    s3 += __shfl_xor(s3, 1); s3 += __shfl_xor(s3, 2); s3 += __shfl_xor(s3, 4);
    if (q == 0) {
        if (layer == 0) { prep[row] = s1; prep[256 + row] = s2; prep[512 + row] = s3; }
        else { prep[1024 + row] = s1; prep[1280 + row] = s2; p3b_ws[row] = s3; }
    }
    if ((blk & 7) == 0) {
        red[t] = layer ? (wcb[t] * ab[t]) : (wca[t] * aa[t]);
        __syncthreads();
        for (int o = 128; o > 0; o >>= 1) { if (t < o) red[t] += red[t + o]; __syncthreads(); }
        if (t == 0) prep[layer ? 1792 : 768] = red[0];
    }
}

// blocks 0..7: wp3b = wtr @ p3b ; blocks 8..39: pack g2_w into MFMA B-fragments
__global__ void prep2_pack(const float* __restrict__ wtr, const float* __restrict__ p3b_ws,
                           float* __restrict__ prep, unsigned short* __restrict__ wfrag) {
    const int t = threadIdx.x, blk = blockIdx.x;
    __shared__ float p3[256];
    if (blk < 8) {
        p3[t] = p3b_ws[t];
        __syncthreads();
        const int row = blk * 32 + (t >> 3), q = t & 7;
        const float* wr = wtr + (size_t)row * DD + q * 32;
        float s = 0.f;
        #pragma unroll
        for (int c = 0; c < 8; c++) {
            float4 v = *(const float4*)&wr[c * 4];
            float4 p = *(const float4*)&p3[q * 32 + c * 4];
            s = fmaf(v.x, p.x, fmaf(v.y, p.y, fmaf(v.z, p.z, fmaf(v.w, p.w, s))));
        }
        s += __shfl_xor(s, 1); s += __shfl_xor(s, 2); s += __shfl_xor(s, 4);
        if (q == 0) prep[1536 + row] = s;
    } else {
        int gid = (blk - 8) * 256 + t;      // 0..8191
        int l = gid & 63, frag = gid >> 6;
        int kc = frag >> 4, nt = frag & 15;
        int kb = kc * 32 + (l >> 4) * 8;
        int n = nt * 16 + (l & 15);
        u16x8 u;
        #pragma unroll
        for (int j = 0; j < 8; j++) u[j] = f2bf(wtr[(size_t)(kb + j) * DD + n]);
        *(u16x8*)(wfrag + (size_t)gid * 8) = u;
    }
}

// One block per batch. Extended-column MFMA: Dn/db2 computed inside the product
// phases (no LDS round-trip); ~14 barriers vs 19.
__launch_bounds__(512, 4)
__global__ void mega(const int* __restrict__ inputs, const int* __restrict__ HT,
                     const float* __restrict__ emb_w, const float* __restrict__ emb2_w,
                     const float* __restrict__ prep, const unsigned short* __restrict__ wfrag,
                     float* __restrict__ out) {
    __shared__ unsigned short bufA[256 * SA];  // x0bf [64][264] -> YT [256][68]
    __shared__ unsigned short RA[64 * SA];     // Pe^T -> M(row)
    __shared__ unsigned short RB[64 * SA];     // Pn'(row)
    __shared__ unsigned short RC[64 * SA];     // Pe row -> C2 row
    __shared__ unsigned short RD[64 * SA];     // C1'^T
    __shared__ unsigned short XT[16 * SA];     // ext B-tile: row0=De, rows1-3=g3,g4,g5
    __shared__ unsigned short pvs[6 * 256];    // p-vectors bf16
    __shared__ float dvs[384];                 // j*64+n
    __shared__ float db2[192];
    __shared__ float u1f[64], invdef[64];
    __shared__ unsigned long long mE[64], mN[64];

    const int b = blockIdx.x;
    const int t = threadIdx.x;
    const int lane = t & 63;
    const int w8 = t >> 6;
    const int l15 = lane & 15, lh = lane >> 4;

    // ---- P1: pvs stage; XT zero; x0 stage; mE ballots; nodes2 -> regs ----
    for (int i = t; i < 1536; i += 512) {
        int off = i + (((i >> 8) >= 3) ? 256 : 0);
        pvs[i] = f2bf(prep[off]);
    }
    for (int i = t; i < 16 * SA; i += 512) XT[i] = 0;
    {
        const int rw = t >> 3, q8 = t & 7;
        const int idx = inputs[b * 64 + rw];
        const float* src = emb_w + (size_t)idx * DD + q8 * 32;
        #pragma unroll
        for (int c = 0; c < 8; c++) {
            float4 v = ((const float4*)src)[c];
            ushort4 u;
            u.x = f2bf(v.x); u.y = f2bf(v.y); u.z = f2bf(v.z); u.w = f2bf(v.w);
            *(ushort4*)&bufA[rw * 264 + q8 * 32 + c * 4] = u;
        }
    }
    float4 n2r[8];   // nodes2 rows (stores deferred)
    #pragma unroll
    for (int c = 0; c < 8; c++) {
        int i = t + 512 * c;
        int n = i >> 6, cc = i & 63;
        int idx = inputs[b * 64 + n];
        n2r[c] = ((const float4*)(emb2_w + (size_t)idx * DD))[cc];
    }
    #pragma unroll
    for (int i = 0; i < 8; i++) {
        int e = w8 * 8 + i;
        int hx = HT[((size_t)b * EE + e) * NN + lane];
        unsigned long long m = __ballot(hx > 0);
        if (lane == 0) mE[e] = m;
    }
    __syncthreads();

    // ---- P1b: dv = x0 @ pvecs via MFMA (waves 0-3) ; mN (wave 4) ----
    if (w8 < 4) {
        const int wtile = w8 * 16;
        const int j = (l15 < 6) ? l15 : 5;
        f4v acc = {0.f, 0.f, 0.f, 0.f};
        #pragma unroll
        for (int kc = 0; kc < 8; kc++) {
            s8v a = *(const s8v*)&bufA[(wtile + l15) * 264 + kc * 32 + lh * 8];
            s8v bv = *(const s8v*)&pvs[j * 256 + kc * 32 + lh * 8];
            acc = __builtin_amdgcn_mfma_f32_16x16x32_bf16(a, bv, acc, 0, 0, 0);
        }
        if (l15 < 6) {
            #pragma unroll
            for (int rg = 0; rg < 4; rg++)
                dvs[l15 * 64 + wtile + lh * 4 + rg] = acc[rg];
        }
    } else if (w8 == 4) {
        unsigned long long acc = 0ull;
        for (int e = 0; e < 64; e++) acc |= ((mE[e] >> lane) & 1ull) << e;
        mN[lane] = acc;
    }
    __syncthreads();

    const int wr = (w8 & 3) * 16;
    const int wc = (w8 >> 2) * 32;
    const int row0 = wr + lh * 4;

    // ================= layer 1 =================
    // ---- P2: Pe1 -> RA (^T) + RC (row) ----
    {
        float s1l = lrelu(prep[768] + dvs[lane]);
        float g1 = s1l;
        #pragma unroll
        for (int o = 32; o > 0; o >>= 1) g1 = fmaxf(g1, __shfl_xor(g1, o));
        float E1 = __expf(s1l - g1);
        #pragma unroll
        for (int i = 0; i < 8; i++) {
            int e = w8 * 8 + i;
            unsigned long long me = mE[e];
            float pe = (me == 0ull) ? 1.f : (((me >> lane) & 1ull) ? E1 : 0.f);
            unsigned short bf = f2bf(pe);
            RA[lane * SA + e] = bf;
            RC[e * SA + lane] = bf;
        }
    }
    __syncthreads();

    // ---- P2b: [De;We;g3;g4;g5] = [1;d2;dv3;dv4;dv5] x Pe^T (MFMA, waves 0-3) ----
    if (w8 < 4) {
        const int etile = w8 * 16;
        f4v acc = {0.f, 0.f, 0.f, 0.f};
        #pragma unroll
        for (int kc = 0; kc < 2; kc++) {
            u16x8 au;
            #pragma unroll
            for (int jj = 0; jj < 8; jj++) {
                int k = kc * 32 + lh * 8 + jj;
                float v = (l15 == 0) ? 1.f : ((l15 <= 4) ? dvs[(l15 + 1) * 64 + k] : 0.f);
                au[jj] = f2bf(v);
            }
            s8v bv = *(const s8v*)&RC[(etile + l15) * SA + kc * 32 + lh * 8];
            acc = __builtin_amdgcn_mfma_f32_16x16x32_bf16((s8v)au, bv, acc, 0, 0, 0);
        }
        int e = etile + l15;
        if (lh == 0) {
            float De = acc[0], We = acc[1];
            invdef[e] = 1.f / De;
            u1f[e] = We / De;
            XT[e] = f2bf(De);                 // row 0
            XT[1 * SA + e] = f2bf(acc[2]);    // g3
            XT[2 * SA + e] = f2bf(acc[3]);    // g4
        } else if (lh == 1) {
            XT[3 * SA + e] = f2bf(acc[0]);    // g5 (A-row 4 -> D[4][e])
        }
    }
    __syncthreads();

    // ---- P3: Pn1' = Pn1 * (1/De) -> RB (row-major) ----
    {
        float t2l = dvs[64 + lane];
        float gt2 = t2l;
        #pragma unroll
        for (int o = 32; o > 0; o >>= 1) gt2 = fmaxf(gt2, __shfl_xor(gt2, o));
        float um = u1f[lane];
        #pragma unroll
        for (int o = 32; o > 0; o >>= 1) um = fmaxf(um, __shfl_xor(um, o));
        float M1 = lrelu(gt2 + um);
        float ul = u1f[lane];
        float ide = invdef[lane];
        #pragma unroll
        for (int i = 0; i < 8; i++) {
            int n = w8 * 8 + i;
            unsigned long long mn = mN[n];
            float t2n = dvs[64 + n];
            float pr = (mn == 0ull) ? 1.f
                     : (((mn >> lane) & 1ull) ? __expf(lrelu(t2n + ul) - M1) : 0.f);
            RB[n * SA + lane] = f2bf(pr * ide);
        }
    }
    __syncthreads();

    // ---- P4: C1' + Dn (ext col0) + db2 (ext cols1-3) -> RD; db2 LDS ----
    {
        f4v a0 = {0.f,0.f,0.f,0.f}, a1 = {0.f,0.f,0.f,0.f}, ax = {0.f,0.f,0.f,0.f};
        #pragma unroll
        for (int kc = 0; kc < 2; kc++) {
            s8v a  = *(const s8v*)&RB[(wr + l15) * SA + kc * 32 + lh * 8];
            s8v b0 = *(const s8v*)&RA[(wc + l15) * SA + kc * 32 + lh * 8];
            s8v b1 = *(const s8v*)&RA[(wc + 16 + l15) * SA + kc * 32 + lh * 8];
            s8v bx = *(const s8v*)&XT[l15 * SA + kc * 32 + lh * 8];
            a0 = __builtin_amdgcn_mfma_f32_16x16x32_bf16(a, b0, a0, 0, 0, 0);
            a1 = __builtin_amdgcn_mfma_f32_16x16x32_bf16(a, b1, a1, 0, 0, 0);
            ax = __builtin_amdgcn_mfma_f32_16x16x32_bf16(a, bx, ax, 0, 0, 0);
        }
        float invdn[4];
        #pragma unroll
        for (int rg = 0; rg < 4; rg++) invdn[rg] = 1.f / __shfl(ax[rg], lh << 4);
        int col0 = wc + l15, col1 = wc + 16 + l15;
        ushort4 u0, u1;
        #pragma unroll
        for (int rg = 0; rg < 4; rg++) {
            ((unsigned short*)&u0)[rg] = f2bf(a0[rg] * invdn[rg] + ((row0 + rg) == col0 ? 1.f : 0.f));
            ((unsigned short*)&u1)[rg] = f2bf(a1[rg] * invdn[rg] + ((row0 + rg) == col1 ? 1.f : 0.f));
        }
        *(ushort4*)&RD[col0 * SA + row0] = u0;
        *(ushort4*)&RD[col1 * SA + row0] = u1;
        if (w8 < 4 && l15 >= 1 && l15 <= 3) {
            int jj = l15 - 1;
            #pragma unroll
            for (int rg = 0; rg < 4; rg++)
                db2[jj * 64 + row0 + rg] = ax[rg] * invdn[rg] + dvs[(jj + 3) * 64 + row0 + rg];
        }
    }
    __syncthreads();

    // ================= layer 2 =================
    // ---- P6: Pe2 -> RA (^T) + RC (row) ----
    {
        float s2l = lrelu(prep[1792] + db2[lane]);
        float g2 = s2l;
        #pragma unroll
        for (int o = 32; o > 0; o >>= 1) g2 = fmaxf(g2, __shfl_xor(g2, o));
        float E2 = __expf(s2l - g2);
        #pragma unroll
        for (int i = 0; i < 8; i++) {
            int e = w8 * 8 + i;
            unsigned long long me = mE[e];
            float pe = (me == 0ull) ? 1.f : (((me >> lane) & 1ull) ? E2 : 0.f);
            unsigned short bf = f2bf(pe);
            RA[lane * SA + e] = bf;
            RC[e * SA + lane] = bf;
        }
    }
    __syncthreads();

    // ---- P6b: [De2;We2] via MFMA (waves 0-3) ; XT row0 = De2 ----
    if (w8 < 4) {
        const int etile = w8 * 16;
        f4v acc = {0.f, 0.f, 0.f, 0.f};
        #pragma unroll
        for (int kc = 0; kc < 2; kc++) {
            u16x8 au;
            #pragma unroll
            for (int jj = 0; jj < 8; jj++) {
                int k = kc * 32 + lh * 8 + jj;
                float v = (l15 == 0) ? 1.f : ((l15 == 1) ? db2[128 + k] : 0.f);
                au[jj] = f2bf(v);
            }
            s8v bv = *(const s8v*)&RC[(etile + l15) * SA + kc * 32 + lh * 8];
            acc = __builtin_amdgcn_mfma_f32_16x16x32_bf16((s8v)au, bv, acc, 0, 0, 0);
        }
        if (lh == 0) {
            int e = etile + l15;
            float De = acc[0], We = acc[1];
            invdef[e] = 1.f / De;
            u1f[e] = We / De;
            XT[e] = f2bf(De);
        }
    }
    __syncthreads();

    // ---- P7: Pn2' -> RB ----
    {
        float d1l = db2[64 + lane];
        float gd1 = d1l;
        #pragma unroll
        for (int o = 32; o > 0; o >>= 1) gd1 = fmaxf(gd1, __shfl_xor(gd1, o));
        float um = u1f[lane];
        #pragma unroll
        for (int o = 32; o > 0; o >>= 1) um = fmaxf(um, __shfl_xor(um, o));
        float M2 = lrelu(gd1 + um);
        float ul = u1f[lane];
        float ide = invdef[lane];
        #pragma unroll
        for (int i = 0; i < 8; i++) {
            int n = w8 * 8 + i;
            unsigned long long mn = mN[n];
            float d1n = db2[64 + n];
            float pr = (mn == 0ull) ? 1.f
                     : (((mn >> lane) & 1ull) ? __expf(lrelu(d1n + ul) - M2) : 0.f);
            RB[n * SA + lane] = f2bf(pr * ide);
        }
    }
    __syncthreads();

    // ---- P8: C2 = Dn2^-1 (Pn2' @ Pe2) (Dn2 via ext col0) -> RC (row-major) ----
    {
        f4v a0 = {0.f,0.f,0.f,0.f}, a1 = {0.f,0.f,0.f,0.f}, ax = {0.f,0.f,0.f,0.f};
        #pragma unroll
        for (int kc = 0; kc < 2; kc++) {
            s8v a  = *(const s8v*)&RB[(wr + l15) * SA + kc * 32 + lh * 8];
            s8v b0 = *(const s8v*)&RA[(wc + l15) * SA + kc * 32 + lh * 8];
            s8v b1 = *(const s8v*)&RA[(wc + 16 + l15) * SA + kc * 32 + lh * 8];
            s8v bx = *(const s8v*)&XT[l15 * SA + kc * 32 + lh * 8];
            a0 = __builtin_amdgcn_mfma_f32_16x16x32_bf16(a, b0, a0, 0, 0, 0);
            a1 = __builtin_amdgcn_mfma_f32_16x16x32_bf16(a, b1, a1, 0, 0, 0);
            ax = __builtin_amdgcn_mfma_f32_16x16x32_bf16(a, bx, ax, 0, 0, 0);
        }
        float invdn[4];
        #pragma unroll
        for (int rg = 0; rg < 4; rg++) invdn[rg] = 1.f / __shfl(ax[rg], lh << 4);
        #pragma unroll
        for (int rg = 0; rg < 4; rg++) {
            RC[(row0 + rg) * SA + wc + l15] = f2bf(a0[rg] * invdn[rg]);
            RC[(row0 + rg) * SA + wc + 16 + l15] = f2bf(a1[rg] * invdn[rg]);
        }
    }
    __syncthreads();

    // ---- P9: M = C2 @ C1' -> RA (row-major) ----
    {
        f4v a0 = {0.f,0.f,0.f,0.f}, a1 = {0.f,0.f,0.f,0.f};
        #pragma unroll
        for (int kc = 0; kc < 2; kc++) {
            s8v a  = *(const s8v*)&RC[(wr + l15) * SA + kc * 32 + lh * 8];
            s8v b0 = *(const s8v*)&RD[(wc + l15) * SA + kc * 32 + lh * 8];
            s8v b1 = *(const s8v*)&RD[(wc + 16 + l15) * SA + kc * 32 + lh * 8];
            a0 = __builtin_amdgcn_mfma_f32_16x16x32_bf16(a, b0, a0, 0, 0, 0);
            a1 = __builtin_amdgcn_mfma_f32_16x16x32_bf16(a, b1, a1, 0, 0, 0);
        }
        #pragma unroll
        for (int rg = 0; rg < 4; rg++) {
            RA[(row0 + rg) * SA + wc + l15] = f2bf(a0[rg]);
            RA[(row0 + rg) * SA + wc + 16 + l15] = f2bf(a1[rg]);
        }
    }
    // nodes2 deferred stores
    #pragma unroll
    for (int c = 0; c < 8; c++) {
        int i = t + 512 * c;
        int n = i >> 6, cc = i & 63;
        ((float4*)(out + (size_t)2 * BND + (size_t)(b * 64 + n) * DD))[cc] = n2r[c];
    }
    __syncthreads();

    // ---- P10: GEMM1 Y = x0 @ w -> YT overlay in bufA ; residual -> regs ----
    const int cb8 = (w8 >> 2) * 8;
    unsigned short rres[8][4];
    {
        f4v acc[8];
        #pragma unroll
        for (int nt = 0; nt < 8; nt++) acc[nt] = (f4v){0.f, 0.f, 0.f, 0.f};
        const s8v* wf = (const s8v*)wfrag;
        #pragma unroll
        for (int kc = 0; kc < 8; kc++) {
            s8v a = *(const s8v*)&bufA[(wr + l15) * 264 + kc * 32 + lh * 8];
            #pragma unroll
            for (int nt = 0; nt < 8; nt++) {
                s8v bv = wf[(size_t)(kc * 16 + cb8 + nt) * 64 + lane];
                acc[nt] = __builtin_amdgcn_mfma_f32_16x16x32_bf16(a, bv, acc[nt], 0, 0, 0);
            }
        }
        #pragma unroll
        for (int nt = 0; nt < 8; nt++) {
            #pragma unroll
            for (int rg = 0; rg < 4; rg++)
                rres[nt][rg] = bufA[(row0 + rg) * 264 + (cb8 + nt) * 16 + l15];
        }
        __syncthreads();   // x0 dead -> YT overlay
        #pragma unroll
        for (int nt = 0; nt < 8; nt++) {
            int feat = (cb8 + nt) * 16 + l15;
            ushort4 u;
            u.x = f2bf(acc[nt][0]); u.y = f2bf(acc[nt][1]);
            u.z = f2bf(acc[nt][2]); u.w = f2bf(acc[nt][3]);
            *(ushort4*)&bufA[feat * SA + row0] = u;
        }
    }
    __syncthreads();

    // ---- P11: out = M @ Y + x0 (residual from regs) ----
    {
        f4v acc2[8];
        #pragma unroll
        for (int nt = 0; nt < 8; nt++) acc2[nt] = (f4v){0.f, 0.f, 0.f, 0.f};
        #pragma unroll
        for (int kc = 0; kc < 2; kc++) {
            s8v a = *(const s8v*)&RA[(wr + l15) * SA + kc * 32 + lh * 8];
            #pragma unroll
            for (int nt = 0; nt < 8; nt++) {
                s8v bv = *(const s8v*)&bufA[((cb8 + nt) * 16 + l15) * SA + kc * 32 + lh * 8];
                acc2[nt] = __builtin_amdgcn_mfma_f32_16x16x32_bf16(a, bv, acc2[nt], 0, 0, 0);
            }
        }
        #pragma unroll
        for (int nt = 0; nt < 8; nt++) {
            #pragma unroll
            for (int rg = 0; rg < 4; rg++) {
                int row = row0 + rg;
                int colg = (cb8 + nt) * 16 + l15;
                float v = acc2[nt][rg] + bf2f(rres[nt][rg]);
                size_t o = (size_t)(b * 64 + row) * DD + colg;
                out[o] = v;
                out[BND + o] = v;
            }
        }
    }
}

extern "C" void kernel_launch(void* const* d_in, const int* in_sizes, int n_in,
                              void* d_out, int out_size, void* d_ws, size_t ws_size,
                              hipStream_t stream) {
    const int* inputs = (const int*)d_in[0];
    const int* HT = (const int*)d_in[1];
    const float* emb_w  = (const float*)d_in[4];
    const float* emb2_w = (const float*)d_in[5];
    const float* g1_w2 = (const float*)d_in[6];
    const float* g1_w3 = (const float*)d_in[7];
    const float* g1_a  = (const float*)d_in[8];
    const float* g1_a2 = (const float*)d_in[9];
    const float* g1_wc = (const float*)d_in[10];
    const float* g2_w  = (const float*)d_in[11];
    const float* g2_w2 = (const float*)d_in[12];
    const float* g2_w3 = (const float*)d_in[13];
    const float* g2_a  = (const float*)d_in[14];
    const float* g2_a2 = (const float*)d_in[15];
    const float* g2_wc = (const float*)d_in[16];

    float* out = (float*)d_out;
    float* prep = (float*)((char*)d_ws + WS_PREP);
    float* p3b_ws = (float*)((char*)d_ws + WS_P3B);
    unsigned short* wfrag = (unsigned short*)((char*)d_ws + WS_WFRAG);

    prep_dots<<<16, 256, 0, stream>>>(g1_w2, g1_w3, g1_a, g1_a2, g1_wc,
                                      g2_w2, g2_w3, g2_a, g2_a2, g2_wc,
                                      prep, p3b_ws);
    prep2_pack<<<40, 256, 0, stream>>>(g2_w, p3b_ws, prep, wfrag);
    mega<<<BB, 512, 0, stream>>>(inputs, HT, emb_w, emb2_w, prep, wfrag, out);
}